// Round 8
// baseline (409.883 us; speedup 1.0000x reference)
//
#include <hip/hip_runtime.h>

#define HH 512
#define WW 1024
#define NC 19
#define HWP (HH * WW)
#define NB 4
#define NREP 4
#define NXCD 8
#define IGNORE_IDX 255

typedef float f2v __attribute__((ext_vector_type(2)));
typedef float f4v __attribute__((ext_vector_type(4)));

__device__ __forceinline__ unsigned pack_h2(float a, float b) {
    unsigned short lo = __builtin_bit_cast(unsigned short, (_Float16)a);
    unsigned short hi = __builtin_bit_cast(unsigned short, (_Float16)b);
    return (unsigned)lo | ((unsigned)hi << 16);
}
__device__ __forceinline__ float unpack_lo(unsigned v) {
    return (float)__builtin_bit_cast(_Float16, (unsigned short)(v & 0xffff));
}
__device__ __forceinline__ float unpack_hi(unsigned v) {
    return (float)__builtin_bit_cast(_Float16, (unsigned short)(v >> 16));
}

#define LDS_P_UINTS (NC * 2048)                   // 19 x 2048 uints = 155648 B
#define LDS_RED_OFF (LDS_P_UINTS * 4)
#define LDS_TOTAL   (LDS_RED_OFF + 16 * NC * 2 * 4)   // + [16][19][2] floats

// Block = 4 consecutive image rows (4096 px), 1024 threads, 4 px/thread.
// Channel-major gather so each channel's ~11-row line footprint is filled
// into L1 once per block (not once per row). p-hat stored fp16 in LDS.
__global__ __launch_bounds__(1024) void tc_main_lds(
    const float* __restrict__ preds,
    const float* __restrict__ targets,
    const float* __restrict__ flow,
    const int* __restrict__ labels,
    float* __restrict__ acc)
{
    extern __shared__ char smem[];
    unsigned* lds_p = (unsigned*)smem;
    float*    red   = (float*)(smem + LDS_RED_OFF);

    const int tid = threadIdx.x;

    // XCD-chunked swizzle: consecutive logical blocks (vertical neighbors,
    // shared halo rows) stay on one XCD's L2.
    const int nwg   = gridDim.x;            // 512
    const int chunk = nwg / NXCD;           // 64
    const int phys  = blockIdx.x;
    const int logical = (phys % NXCD) * chunk + phys / NXCD;

    const int b    = logical >> 7;          // 128 blocks per image
    const int blk  = logical & 127;
    const int base = blk * 4 * WW;          // first pixel of the 4-row slab

    const float* tb = targets + (size_t)b * NC * HWP;
    const float* pb = preds   + (size_t)b * NC * HWP;
    const float* fb = flow    + (size_t)b * HWP * 2;
    const int*   lb = labels  + (size_t)b * HWP;

    // ---- Phase A: warp indices + validity for this thread's 4 px ----
    // px: k=0 -> 2t, k=1 -> 2t+1, k=2 -> 2t+2048, k=3 -> 2t+2049
    int   sp[4];
    float vf[4];
#pragma unroll
    for (int pr = 0; pr < 2; ++pr) {
        const int lpx = 2 * tid + pr * 2048;
        const int pix = base + lpx;
        const int y = pix >> 10;
        const int x = pix & (WW - 1);
        const f4v f = *(const f4v*)(fb + (size_t)pix * 2);  // dx0,dy0,dx1,dy1
#pragma unroll
        for (int e = 0; e < 2; ++e) {
            const float dx = e ? f.z : f.x;
            const float dy = e ? f.w : f.y;
            const int rx = (int)rintf((float)(x + e) + dx);  // half-even
            const int ry = (int)rintf((float)y + dy);
            const bool valid = (rx >= 0) && (rx < WW) && (ry >= 0) && (ry < HH);
            sp[pr * 2 + e] = min(max(ry, 0), HH - 1) * WW + min(max(rx, 0), WW - 1);
            vf[pr * 2 + e] = valid ? 1.f : 0.f;
        }
    }

    // ---- Phase B: channel-major gather + exp -> packed fp16 in LDS ----
    float psum[4] = {0.f, 0.f, 0.f, 0.f};
#pragma unroll
    for (int c = 0; c < NC; ++c) {
        const float* pc = pb + (size_t)c * HWP;
        float e0 = __expf(pc[sp[0]]);
        float e1 = __expf(pc[sp[1]]);
        float e2 = __expf(pc[sp[2]]);
        float e3 = __expf(pc[sp[3]]);
        psum[0] += e0; psum[1] += e1; psum[2] += e2; psum[3] += e3;
        lds_p[c * 2048 + tid]        = pack_h2(e0, e1);
        lds_p[c * 2048 + 1024 + tid] = pack_h2(e2, e3);
    }
    float pinv[4];
#pragma unroll
    for (int k = 0; k < 4; ++k) pinv[k] = vf[k] / psum[k];

    __syncthreads();

    // ---- Phase C: targets softmax + IoU accumulate (per pixel-pair) ----
    float accn[NC], accd[NC];
#pragma unroll
    for (int c = 0; c < NC; ++c) { accn[c] = 0.f; accd[c] = 0.f; }

#pragma unroll
    for (int pr = 0; pr < 2; ++pr) {
        const int lpx = 2 * tid + pr * 2048;
        const int pix = base + lpx;

        const int2 lab = *(const int2*)(lb + pix);
        const float keep0 = (lab.x != IGNORE_IDX) ? 1.f : 0.f;
        const float keep1 = (lab.y != IGNORE_IDX) ? 1.f : 0.f;

        f2v te[NC];
        float ts0 = 0.f, ts1 = 0.f;
#pragma unroll
        for (int c = 0; c < NC; ++c) {
            const f2v v = *(const f2v*)(tb + (size_t)c * HWP + pix);
            te[c].x = __expf(v.x); ts0 += te[c].x;
            te[c].y = __expf(v.y); ts1 += te[c].y;
        }
        const float ti0 = keep0 / ts0;
        const float ti1 = keep1 / ts1;
        const float pi0 = pinv[pr * 2];
        const float pi1 = pinv[pr * 2 + 1];

#pragma unroll
        for (int c = 0; c < NC; ++c) {
            const unsigned u = lds_p[c * 2048 + pr * 1024 + tid];
            const float p0 = unpack_lo(u) * pi0;
            const float p1 = unpack_hi(u) * pi1;
            const float t0 = te[c].x * ti0;
            const float t1 = te[c].y * ti1;
            const float pt0 = p0 * t0;
            const float pt1 = p1 * t1;
            accn[c] += pt0 + pt1;
            accd[c] += (p0 + t0 - pt0) + (p1 + t1 - pt1);
        }
    }

    // ---- reduction: wave shuffle -> LDS -> atomics ----
#pragma unroll
    for (int c = 0; c < NC; ++c) {
        for (int off = 32; off > 0; off >>= 1) {
            accn[c] += __shfl_xor(accn[c], off);
            accd[c] += __shfl_xor(accd[c], off);
        }
    }
    __syncthreads();   // done reading lds_p; red aliases fresh area
    const int wave = tid >> 6;
    const int lane = tid & 63;
    if (lane == 0) {
#pragma unroll
        for (int c = 0; c < NC; ++c) {
            red[(wave * NC + c) * 2 + 0] = accn[c];
            red[(wave * NC + c) * 2 + 1] = accd[c];
        }
    }
    __syncthreads();
    if (tid < NC * 2) {
        const int c = tid >> 1;
        const int wh = tid & 1;
        float v = 0.f;
#pragma unroll
        for (int wv = 0; wv < 16; ++wv) v += red[(wv * NC + c) * 2 + wh];
        const int rep = phys & (NREP - 1);
        atomicAdd(&acc[(((size_t)rep * NB + b) * NC + c) * 2 + wh], v);
    }
}

// ---- Fallback: R4 kernel (103 us) if big dynamic LDS is unavailable ----
__global__ __launch_bounds__(256) void tc_main_direct(
    const float* __restrict__ preds,
    const float* __restrict__ targets,
    const float* __restrict__ flow,
    const int* __restrict__ labels,
    float* __restrict__ acc)
{
    const int tid = threadIdx.x;
    const int nwg   = gridDim.x;
    const int chunk = nwg / NXCD;
    const int phys  = blockIdx.x;
    const int logical = (phys % NXCD) * chunk + phys / NXCD;
    const int blocks_per_img = nwg / NB;
    const int b   = logical / blocks_per_img;
    const int blk = logical % blocks_per_img;

    float accn[NC], accd[NC];
#pragma unroll
    for (int c = 0; c < NC; ++c) { accn[c] = 0.f; accd[c] = 0.f; }

    const float* tb = targets + (size_t)b * NC * HWP;
    const float* pb = preds   + (size_t)b * NC * HWP;
    const f2v*   fb = (const f2v*)(flow + (size_t)b * HWP * 2);
    const int*   lb = labels  + (size_t)b * HWP;

    const int per_block = HWP / blocks_per_img;
    const int base = blk * per_block;

    for (int k = tid; k < per_block; k += 256) {
        const int pix = base + k;
        const int y = pix >> 10;
        const int x = pix & (WW - 1);
        const f2v f = __builtin_nontemporal_load(&fb[pix]);
        const int rx = (int)rintf((float)x + f.x);
        const int ry = (int)rintf((float)y + f.y);
        const bool valid = (rx >= 0) && (rx < WW) && (ry >= 0) && (ry < HH);
        const int spix = min(max(ry, 0), HH - 1) * WW + min(max(rx, 0), WW - 1);
        const bool keep = (__builtin_nontemporal_load(&lb[pix]) != IGNORE_IDX);

        float te[NC], pe[NC];
        float tsum = 0.f, psum = 0.f;
#pragma unroll
        for (int c = 0; c < NC; ++c) {
            te[c] = __expf(__builtin_nontemporal_load(&tb[(size_t)c * HWP + pix]));
            tsum += te[c];
        }
#pragma unroll
        for (int c = 0; c < NC; ++c) {
            pe[c] = __expf(pb[(size_t)c * HWP + spix]);
            psum += pe[c];
        }
        const float tinv = keep  ? (1.0f / tsum) : 0.0f;
        const float pinv = valid ? (1.0f / psum) : 0.0f;
#pragma unroll
        for (int c = 0; c < NC; ++c) {
            const float t = te[c] * tinv;
            const float p = pe[c] * pinv;
            const float pt = p * t;
            accn[c] += pt;
            accd[c] += p + t - pt;
        }
    }

#pragma unroll
    for (int c = 0; c < NC; ++c) {
        for (int off = 32; off > 0; off >>= 1) {
            accn[c] += __shfl_xor(accn[c], off);
            accd[c] += __shfl_xor(accd[c], off);
        }
    }
    __shared__ float s[4][NC][2];
    const int wave = tid >> 6;
    const int lane = tid & 63;
    if (lane == 0) {
#pragma unroll
        for (int c = 0; c < NC; ++c) { s[wave][c][0] = accn[c]; s[wave][c][1] = accd[c]; }
    }
    __syncthreads();
    if (tid < NC * 2) {
        const int c = tid >> 1;
        const int which = tid & 1;
        const float v = s[0][c][which] + s[1][c][which] + s[2][c][which] + s[3][c][which];
        const int rep = phys & (NREP - 1);
        atomicAdd(&acc[(((size_t)rep * NB + b) * NC + c) * 2 + which], v);
    }
}

__global__ void tc_final(const float* __restrict__ acc, float* __restrict__ out)
{
    if (threadIdx.x == 0 && blockIdx.x == 0) {
        float total = 0.f;
        for (int b = 0; b < NB; ++b) {
            float m = 0.f;
            for (int c = 0; c < NC; ++c) {
                float n = 0.f, d = 0.f;
                for (int r = 0; r < NREP; ++r) {
                    n += acc[(((size_t)r * NB + b) * NC + c) * 2 + 0];
                    d += acc[(((size_t)r * NB + b) * NC + c) * 2 + 1];
                }
                m += n / d;
            }
            total += 1.0f - m / (float)NC;
        }
        out[0] = total / (float)NB;
    }
}

extern "C" void kernel_launch(void* const* d_in, const int* in_sizes, int n_in,
                              void* d_out, int out_size, void* d_ws, size_t ws_size,
                              hipStream_t stream) {
    const float* preds   = (const float*)d_in[0];
    const float* targets = (const float*)d_in[1];
    const float* flow    = (const float*)d_in[2];
    const int*   labels  = (const int*)d_in[3];
    float* acc = (float*)d_ws;

    hipMemsetAsync(acc, 0, (size_t)NREP * NB * NC * 2 * sizeof(float), stream);

    static hipError_t attr_ok = hipFuncSetAttribute(
        reinterpret_cast<const void*>(tc_main_lds),
        hipFuncAttributeMaxDynamicSharedMemorySize, LDS_TOTAL);

    if (attr_ok == hipSuccess) {
        tc_main_lds<<<512, 1024, LDS_TOTAL, stream>>>(preds, targets, flow, labels, acc);
    } else {
        tc_main_direct<<<2048, 256, 0, stream>>>(preds, targets, flow, labels, acc);
    }
    tc_final<<<1, 64, 0, stream>>>(acc, (float*)d_out);
}